// Round 9
// baseline (507.182 us; speedup 1.0000x reference)
//
#include <hip/hip_runtime.h>

#define NN 100000
#define NE 1600000
#define CH 4096                                  // edges per chunk (build)
#define NCHUNK ((NE + CH - 1) / CH)              // 391
#define NBUCK ((NN + 255) / 256)                 // 391 (256-node buckets = fused blocks)
#define GGRID 1563                               // gathx blocks: 1563*256*4 >= NE
#define GT (GGRID * 256)                         // 400128 gather threads

__device__ __forceinline__ float wave_red(float v) {
#pragma unroll
    for (int off = 32; off > 0; off >>= 1) v += __shfl_down(v, off, 64);
    return v;
}

// ---------------- build phase: bucket sort, zero global atomics --------------
__global__ __launch_bounds__(256) void hist_kernel(
    const int* __restrict__ ei, int* __restrict__ hist)
{
    __shared__ int h[NBUCK];
    int t = threadIdx.x, c = blockIdx.x;
    for (int b = t; b < NBUCK; b += 256) h[b] = 0;
    __syncthreads();
    int base = c * CH;
    for (int i = t; i < CH; i += 256) {
        int e = base + i;
        if (e < NE) atomicAdd(&h[ei[e] >> 8], 1);
    }
    __syncthreads();
    for (int b = t; b < NBUCK; b += 256) hist[c * NBUCK + b] = h[b];
}

__global__ __launch_bounds__(512) void bscan_kernel(
    const int* __restrict__ hist, int* __restrict__ baseT, int* __restrict__ colTotal)
{
    __shared__ int buf[2][512];
    int b = blockIdx.x, t = threadIdx.x;
    int v = (t < NCHUNK) ? hist[t * NBUCK + b] : 0;
    buf[0][t] = v;
    __syncthreads();
    int src = 0;
    for (int d = 1; d < 512; d <<= 1) {
        int nv = buf[src][t] + ((t >= d) ? buf[src][t - d] : 0);
        buf[src ^ 1][t] = nv;
        src ^= 1;
        __syncthreads();
    }
    if (t < NCHUNK) baseT[b * NCHUNK + t] = buf[src][t] - v;   // exclusive over chunks
    if (t == NCHUNK - 1) colTotal[b] = buf[src][t];
}

__global__ __launch_bounds__(512) void boff_kernel(
    const int* __restrict__ colTotal, int* __restrict__ b_off)
{
    __shared__ int buf[2][512];
    int t = threadIdx.x;
    int v = (t < NBUCK) ? colTotal[t] : 0;
    buf[0][t] = v;
    __syncthreads();
    int src = 0;
    for (int d = 1; d < 512; d <<= 1) {
        int nv = buf[src][t] + ((t >= d) ? buf[src][t - d] : 0);
        buf[src ^ 1][t] = nv;
        src ^= 1;
        __syncthreads();
    }
    if (t < NBUCK) b_off[t] = buf[src][t] - v;
    if (t == NBUCK - 1) b_off[NBUCK] = buf[src][t];            // = NE
}

// rec[slot] = {key = (li<<17)|col, spare, ea0/emb0, ea1/emb1}  (16B, one line touch)
__global__ __launch_bounds__(256) void fillb_kernel(
    const int* __restrict__ ei, const float* __restrict__ eattr,
    const int* __restrict__ baseT, const int* __restrict__ b_off,
    float4* __restrict__ rec)
{
    __shared__ int sslot[NBUCK];
    int t = threadIdx.x, c = blockIdx.x;
    for (int b = t; b < NBUCK; b += 256)
        sslot[b] = b_off[b] + baseT[b * NCHUNK + c];
    __syncthreads();
    int base = c * CH;
    for (int i = t; i < CH; i += 256) {
        int e = base + i;
        if (e < NE) {
            int row = ei[e];
            int slot = atomicAdd(&sslot[row >> 8], 1);
            float2 ea = reinterpret_cast<const float2*>(eattr)[e];
            float4 v;
            v.x = __int_as_float(((row & 255) << 17) | ei[NE + e]);
            v.y = 0.f; v.z = ea.x; v.w = ea.y;
            rec[slot] = v;
        }
    }
}

// ============ gathx: ISOLATED gather pass, per layer =========================
// r0-r8: per-edge cost pinned ~23cyc; surviving suspect is the in-loop random
// x[col] gather, bounded by outstanding-miss capacity per CU (compute waves
// hold ~1 dependent gather in flight each). This kernel is nothing but
// gathers: 4 independent per thread, tiny VGPR, no LDS -> maximal misses in
// flight. Reads rec (coalesced, key only), writes gathA/B (coalesced SoA).
__global__ __launch_bounds__(256) void gathx_kernel(
    const float4* __restrict__ rec, const float* __restrict__ xin,
    float4* __restrict__ gA, float4* __restrict__ gB)
{
    int t = blockIdx.x * 256 + threadIdx.x;
    bool v[4]; float4 r[4];
#pragma unroll
    for (int k = 0; k < 4; k++) {
        int s = t + k * GT;
        v[k] = (s < NE);
        if (v[k]) r[k] = rec[s];
    }
    float4 a[4], b[4];
#pragma unroll
    for (int k = 0; k < 4; k++) {
        if (v[k]) {
            int col = __float_as_int(r[k].x) & 0x1FFFF;
            const float4* p = reinterpret_cast<const float4*>(xin + (size_t)col * 8);
            a[k] = p[0]; b[k] = p[1];
        }
    }
#pragma unroll
    for (int k = 0; k < 4; k++) {
        if (v[k]) {
            int s = t + k * GT;
            gA[s] = a[k]; gB[s] = b[k];
        }
    }
}

// ============ FUSED layer kernel: pure streaming (gather pre-materialized) ===
// All global reads are unit-stride: rec (key+attr/emb), gathA/B (x[col] rows).
// No dependent random load anywhere in the edge loop.
template <bool WRITE_EMB, bool NEED_SUM>
__global__ __launch_bounds__(512) void fused_kernel(
    float4* __restrict__ rec,
    const float4* __restrict__ gA, const float4* __restrict__ gB,
    const int* __restrict__ b_off,
    const float* __restrict__ gptr,
    const float* __restrict__ eW1, const float* __restrict__ eB1,
    const float* __restrict__ eW2, const float* __restrict__ eB2,
    const float* __restrict__ xin,
    const float* __restrict__ nW1, const float* __restrict__ nB1,
    const float* __restrict__ nW2, const float* __restrict__ nB2,
    float* __restrict__ xout, float* __restrict__ sums)
{
    __shared__ float sPr[256][20];               // 20KB, padded, b128-aligned rows
    __shared__ float sagg[256][2];               // 2KB
    __shared__ float redE[8][2];
    __shared__ float redN[4][8];
    int tid = threadIdx.x;
    ((float*)sagg)[tid] = 0.f;                   // 512 threads cover 512 floats

    int n0 = blockIdx.x * 256;
    float gval = gptr[0];
    bool own = (tid < 256) && (n0 + tid < NN);
    float xv[8];
    if (own) {
        const float4* xi = reinterpret_cast<const float4*>(xin + (size_t)(n0 + tid) * 8);
        float4 a0 = xi[0], a1 = xi[1];
        xv[0] = a0.x; xv[1] = a0.y; xv[2] = a0.z; xv[3] = a0.w;
        xv[4] = a1.x; xv[5] = a1.y; xv[6] = a1.z; xv[7] = a1.w;
        float pr[16];
#pragma unroll
        for (int q = 0; q < 16; q++) pr[q] = 0.f;
#pragma unroll
        for (int k = 0; k < 8; k++) {
            float v = xv[k];
#pragma unroll
            for (int q = 0; q < 16; q++) pr[q] += v * eW1[(1 + k) * 16 + q];
        }
        float4* pw = reinterpret_cast<float4*>(&sPr[tid][0]);
#pragma unroll
        for (int t4 = 0; t4 < 4; t4++)
            pw[t4] = make_float4(pr[4*t4], pr[4*t4+1], pr[4*t4+2], pr[4*t4+3]);
    }
    __syncthreads();

    int e0 = b_off[blockIdx.x], e1 = b_off[blockIdx.x + 1];

    float gterm[16];
#pragma unroll
    for (int q = 0; q < 16; q++) gterm[q] = eB1[q] + gval * eW1[q];

    float t0 = 0.f, t1 = 0.f;
    for (int e = e0 + tid; e < e1; e += 512) {
        float4 r  = rec[e];
        float4 ca = gA[e];
        float4 cb = gB[e];
        int key = __float_as_int(r.x);
        int li  = key >> 17;
        float ea0 = r.z, ea1 = r.w;
        const float4* pr4 = reinterpret_cast<const float4*>(&sPr[li][0]);
        float4 p0 = pr4[0], p1 = pr4[1], p2 = pr4[2], p3 = pr4[3];
        float h[16];
        h[0]  = gterm[0]  + p0.x; h[1]  = gterm[1]  + p0.y;
        h[2]  = gterm[2]  + p0.z; h[3]  = gterm[3]  + p0.w;
        h[4]  = gterm[4]  + p1.x; h[5]  = gterm[5]  + p1.y;
        h[6]  = gterm[6]  + p1.z; h[7]  = gterm[7]  + p1.w;
        h[8]  = gterm[8]  + p2.x; h[9]  = gterm[9]  + p2.y;
        h[10] = gterm[10] + p2.z; h[11] = gterm[11] + p2.w;
        h[12] = gterm[12] + p3.x; h[13] = gterm[13] + p3.y;
        h[14] = gterm[14] + p3.z; h[15] = gterm[15] + p3.w;
        float xc[8] = {ca.x, ca.y, ca.z, ca.w, cb.x, cb.y, cb.z, cb.w};
#pragma unroll
        for (int kk = 0; kk < 8; kk++) {
            float v = xc[kk];
#pragma unroll
            for (int q = 0; q < 16; q++) h[q] += v * eW1[(9 + kk) * 16 + q];
        }
#pragma unroll
        for (int q = 0; q < 16; q++) {
            h[q] += ea0 * eW1[17 * 16 + q];
            h[q] += ea1 * eW1[18 * 16 + q];
        }
        float s0 = eB2[0], s1 = eB2[1];
#pragma unroll
        for (int q = 0; q < 16; q++) {
            float rr = fmaxf(h[q], 0.f);
            s0 += rr * eW2[2 * q];
            s1 += rr * eW2[2 * q + 1];
        }
        if (WRITE_EMB)
            reinterpret_cast<float2*>(rec)[2 * e + 1] = make_float2(s0, s1);
        atomicAdd(&sagg[li][0], s0);
        atomicAdd(&sagg[li][1], s1);
        t0 += s0; t1 += s1;
    }

    if (NEED_SUM) {
        float r0 = wave_red(t0), r1 = wave_red(t1);
        int wave = tid >> 6, lane = tid & 63;
        if (lane == 0) { redE[wave][0] = r0; redE[wave][1] = r1; }
    }
    __syncthreads();   // sagg complete (and redE visible)
    if (NEED_SUM && tid == 0) {
        float s0 = 0.f, s1 = 0.f;
#pragma unroll
        for (int w = 0; w < 8; w++) { s0 += redE[w][0]; s1 += redE[w][1]; }
        atomicAdd(&sums[0], s0);
        atomicAdd(&sums[1], s1);
    }

    // ---------------- phase 2: node MLP (owner threads 0..255) ----------------
    float out[8];
#pragma unroll
    for (int m = 0; m < 8; m++) out[m] = 0.f;

    if (own) {
        int n = n0 + tid;
        float in[11];
        in[0] = gval;
#pragma unroll
        for (int k = 0; k < 8; k++) in[1 + k] = xv[k];
        in[9] = sagg[tid][0]; in[10] = sagg[tid][1];

        float h[16];
#pragma unroll
        for (int q = 0; q < 16; q++) h[q] = nB1[q];
#pragma unroll
        for (int k = 0; k < 11; k++) {
            float v = in[k];
#pragma unroll
            for (int q = 0; q < 16; q++) h[q] += v * nW1[k * 16 + q];
        }
#pragma unroll
        for (int m = 0; m < 8; m++) out[m] = nB2[m];
#pragma unroll
        for (int q = 0; q < 16; q++) {
            float hq = fmaxf(h[q], 0.f);
#pragma unroll
            for (int m = 0; m < 8; m++) out[m] += hq * nW2[q * 8 + m];
        }
        float4* xo = reinterpret_cast<float4*>(xout + (size_t)n * 8);
        xo[0] = make_float4(out[0], out[1], out[2], out[3]);
        xo[1] = make_float4(out[4], out[5], out[6], out[7]);
    }
    if (NEED_SUM) {
        float r[8];
#pragma unroll
        for (int m = 0; m < 8; m++) r[m] = wave_red(out[m]);
        int wave = tid >> 6, lane = tid & 63;
        if (wave < 4 && lane == 0) {
#pragma unroll
            for (int m = 0; m < 8; m++) redN[wave][m] = r[m];
        }
        __syncthreads();
        if (tid == 0) {
#pragma unroll
            for (int m = 0; m < 8; m++) {
                float s = redN[0][m] + redN[1][m] + redN[2][m] + redN[3][m];
                atomicAdd(&sums[2 + m], s);
            }
        }
    }
}

// ---------------- global block: MLP(11->16->1), single thread ----------------
__global__ void glob_kernel(const float* __restrict__ sums,
                            const float* __restrict__ gold,
                            const float* __restrict__ W1, const float* __restrict__ B1,
                            const float* __restrict__ W2, const float* __restrict__ B2,
                            float* __restrict__ gnew)
{
    if (threadIdx.x == 0 && blockIdx.x == 0) {
        float in[11];
#pragma unroll
        for (int j = 0; j < 8; j++) in[j] = sums[2 + j] * (1.0f / NN);
        in[8] = sums[0] * (1.0f / NE);
        in[9] = sums[1] * (1.0f / NE);
        in[10] = gold[0];
        float acc = B2[0];
#pragma unroll
        for (int j = 0; j < 16; j++) {
            float h = B1[j];
#pragma unroll
            for (int k = 0; k < 11; k++) h += in[k] * W1[k * 16 + j];
            acc += fmaxf(h, 0.f) * W2[j];
        }
        gnew[0] = acc;
    }
}

extern "C" void kernel_launch(void* const* d_in, const int* in_sizes, int n_in,
                              void* d_out, int out_size, void* d_ws, size_t ws_size,
                              hipStream_t stream) {
    const float* x     = (const float*)d_in[0];
    const int*   ei    = (const int*)d_in[1];
    const float* eattr = (const float*)d_in[2];
    const float* g     = (const float*)d_in[3];
    const float* eW1 = (const float*)d_in[4];
    const float* eB1 = (const float*)d_in[5];
    const float* eW2 = (const float*)d_in[6];
    const float* eB2 = (const float*)d_in[7];
    const float* nW1 = (const float*)d_in[8];
    const float* nB1 = (const float*)d_in[9];
    const float* nW2 = (const float*)d_in[10];
    const float* nB2 = (const float*)d_in[11];
    const float* gW1 = (const float*)d_in[12];
    const float* gB1 = (const float*)d_in[13];
    const float* gW2 = (const float*)d_in[14];
    const float* gB2 = (const float*)d_in[15];
    float* out = (float*)d_out;

    char* ws = (char*)d_ws;
    float*  xb0   = (float*)(ws);                  // 3,200,000
    float*  xb1   = (float*)(ws + 3200000);        // 3,200,000 -> 6,400,000
    int*    b_off = (int*)  (ws + 6400000);        // 392*4 -> pad 1,600
    float*  sums  = (float*)(ws + 6401600);        // 128 B
    float*  g1    = (float*)(ws + 6401728);
    float*  g2    = g1 + 1;
    float4* rec   = (float4*)(ws + 6401792);       // 25,600,000 -> 32,001,792
    float4* gA    = (float4*)(ws + 32001792);      // 25,600,000 -> 57,601,792
    float4* gB    = (float4*)(ws + 57601792);      // 25,600,000 -> 83,201,792 total
    // build-phase temporaries alias xb1 (dead until layer-1 phase 2):
    int*    hist     = (int*)xb1;                          // 391*391*4 = 611,524
    int*    baseT    = (int*)((char*)xb1 + 611584);        // 611,524
    int*    colTotal = (int*)((char*)xb1 + 1223168);       // 1,564

    dim3 blk(256);
    dim3 fblk(512);
    dim3 cgrid(NCHUNK);                            // 391 chunks
    dim3 bgrid(NBUCK);                             // 391 buckets
    dim3 ggrid(GGRID);                             // 1563 gather blocks

    // ---- bucket-sort build (no global atomics) ----
    hipMemsetAsync(sums, 0, 128, stream);
    hist_kernel<<<cgrid, blk, 0, stream>>>(ei, hist);
    bscan_kernel<<<bgrid, 512, 0, stream>>>(hist, baseT, colTotal);
    boff_kernel<<<1, 512, 0, stream>>>(colTotal, b_off);
    fillb_kernel<<<cgrid, blk, 0, stream>>>(ei, eattr, baseT, b_off, rec);

    // ---- layer 0: gather from x(d_in); fused -> xb0; rec.zw: ea -> L0 emb ----
    gathx_kernel<<<ggrid, blk, 0, stream>>>(rec, x, gA, gB);
    fused_kernel<true, true><<<bgrid, fblk, 0, stream>>>(
        rec, gA, gB, b_off, g,
        eW1, eB1, eW2, eB2,
        x, nW1, nB1, nW2, nB2,
        xb0, sums);
    glob_kernel<<<1, 64, 0, stream>>>(sums, g, gW1, gB1, gW2, gB2, g1);

    // ---- layer 1: gather from xb0; fused -> xb1; rec.zw: L0 -> L1 emb ----
    gathx_kernel<<<ggrid, blk, 0, stream>>>(rec, xb0, gA, gB);
    fused_kernel<true, true><<<bgrid, fblk, 0, stream>>>(
        rec, gA, gB, b_off, g1,
        eW1 + 304, eB1 + 16, eW2 + 32, eB2 + 2,
        xb0, nW1 + 176, nB1 + 16, nW2 + 128, nB2 + 8,
        xb1, sums + 16);
    glob_kernel<<<1, 64, 0, stream>>>(sums + 16, g1, gW1 + 176, gB1 + 16, gW2 + 16, gB2 + 1, g2);

    // ---- layer 2: gather from xb1; fused -> d_out; no emb write, no sums ----
    gathx_kernel<<<ggrid, blk, 0, stream>>>(rec, xb1, gA, gB);
    fused_kernel<false, false><<<bgrid, fblk, 0, stream>>>(
        rec, gA, gB, b_off, g2,
        eW1 + 608, eB1 + 32, eW2 + 64, eB2 + 4,
        xb1, nW1 + 352, nB1 + 32, nW2 + 256, nB2 + 16,
        out, sums);
}

// Round 10
// 387.957 us; speedup vs baseline: 1.3073x; 1.3073x over previous
//
#include <hip/hip_runtime.h>

#define NN 100000
#define NE 1600000
#define CH 4096                                  // edges per chunk (build)
#define NCHUNK ((NE + CH - 1) / CH)              // 391
#define NBUCK ((NN + 255) / 256)                 // 391 (256-node buckets)
#define SUB 4                                    // edge sub-blocks per bucket

__device__ __forceinline__ float wave_red(float v) {
#pragma unroll
    for (int off = 32; off > 0; off >>= 1) v += __shfl_down(v, off, 64);
    return v;
}

// ---------------- build phase: bucket sort, zero global atomics --------------
__global__ __launch_bounds__(256) void hist_kernel(
    const int* __restrict__ ei, int* __restrict__ hist)
{
    __shared__ int h[NBUCK];
    int t = threadIdx.x, c = blockIdx.x;
    for (int b = t; b < NBUCK; b += 256) h[b] = 0;
    __syncthreads();
    int base = c * CH;
    for (int i = t; i < CH; i += 256) {
        int e = base + i;
        if (e < NE) atomicAdd(&h[ei[e] >> 8], 1);
    }
    __syncthreads();
    for (int b = t; b < NBUCK; b += 256) hist[c * NBUCK + b] = h[b];
}

__global__ __launch_bounds__(512) void bscan_kernel(
    const int* __restrict__ hist, int* __restrict__ baseT, int* __restrict__ colTotal)
{
    __shared__ int buf[2][512];
    int b = blockIdx.x, t = threadIdx.x;
    int v = (t < NCHUNK) ? hist[t * NBUCK + b] : 0;
    buf[0][t] = v;
    __syncthreads();
    int src = 0;
    for (int d = 1; d < 512; d <<= 1) {
        int nv = buf[src][t] + ((t >= d) ? buf[src][t - d] : 0);
        buf[src ^ 1][t] = nv;
        src ^= 1;
        __syncthreads();
    }
    if (t < NCHUNK) baseT[b * NCHUNK + t] = buf[src][t] - v;   // exclusive over chunks
    if (t == NCHUNK - 1) colTotal[b] = buf[src][t];
}

__global__ __launch_bounds__(512) void boff_kernel(
    const int* __restrict__ colTotal, int* __restrict__ b_off)
{
    __shared__ int buf[2][512];
    int t = threadIdx.x;
    int v = (t < NBUCK) ? colTotal[t] : 0;
    buf[0][t] = v;
    __syncthreads();
    int src = 0;
    for (int d = 1; d < 512; d <<= 1) {
        int nv = buf[src][t] + ((t >= d) ? buf[src][t - d] : 0);
        buf[src ^ 1][t] = nv;
        src ^= 1;
        __syncthreads();
    }
    if (t < NBUCK) b_off[t] = buf[src][t] - v;
    if (t == NBUCK - 1) b_off[NBUCK] = buf[src][t];            // = NE
}

__global__ __launch_bounds__(256) void fillb_kernel(
    const int* __restrict__ ei, const float* __restrict__ eattr,
    const int* __restrict__ baseT, const int* __restrict__ b_off,
    float4* __restrict__ rec)
{
    __shared__ int sslot[NBUCK];
    int t = threadIdx.x, c = blockIdx.x;
    for (int b = t; b < NBUCK; b += 256)
        sslot[b] = b_off[b] + baseT[b * NCHUNK + c];
    __syncthreads();
    int base = c * CH;
    for (int i = t; i < CH; i += 256) {
        int e = base + i;
        if (e < NE) {
            int row = ei[e];
            int slot = atomicAdd(&sslot[row >> 8], 1);
            float2 ea = reinterpret_cast<const float2*>(eattr)[e];
            float4 v;
            v.x = __int_as_float(row);
            v.y = __int_as_float(ei[NE + e]);
            v.z = ea.x; v.w = ea.y;
            rec[slot] = v;
        }
    }
}

// ============ edge kernel: REGISTER-RESIDENT weights, bucket sub-split =======
// r9 isolated the bottleneck to the streaming MLP loop itself (fused without
// any gather: still 83us). At VGPR=40/SGPR=112 the 208 loop-invariant weights
// cannot be register-resident -> ~200 operand re-fetches from K$/L2 per edge
// iteration, waitcnt-chopping the FMA stream (the one invariant r0-r9 never
// touched). Fix: explicit cw/aw/ow/gterm register arrays loaded ONCE, static
// indexing, launch_bounds(256,1). Occupancy drops to ~2 waves/SIMD -> split
// each bucket across SUB=4 blocks (grid 1564, balanced) with global partial
// aggregates (3.2MB total - NOT r3's per-edge atomics).
template <bool WRITE_EMB, bool NEED_SUM>
__global__ __launch_bounds__(256, 1) void edge_kernel(
    float4* __restrict__ rec, const int* __restrict__ b_off,
    const float* __restrict__ gptr,
    const float* __restrict__ eW1, const float* __restrict__ eB1,
    const float* __restrict__ eW2, const float* __restrict__ eB2,
    const float* __restrict__ xin,
    float2* __restrict__ pagg, float* __restrict__ sums)
{
    __shared__ float sPr[256][20];               // padded rows, b128-aligned
    __shared__ float sagg[256][2];
    __shared__ float redE[4][2];
    int tid = threadIdx.x;
    int b = blockIdx.x >> 2, s = blockIdx.x & 3;
    int n0 = b << 8;
    sagg[tid][0] = 0.f; sagg[tid][1] = 0.f;

    float gval = gptr[0];
    int nrow = n0 + tid;
    if (nrow < NN) {
        // row-projection for own node (once per block; refetch here is fine)
        const float4* xi = reinterpret_cast<const float4*>(xin + (size_t)nrow * 8);
        float4 a0 = xi[0], a1 = xi[1];
        float xv[8] = {a0.x, a0.y, a0.z, a0.w, a1.x, a1.y, a1.z, a1.w};
        float pr[16];
#pragma unroll
        for (int q = 0; q < 16; q++) pr[q] = 0.f;
#pragma unroll
        for (int k = 0; k < 8; k++) {
            float v = xv[k];
#pragma unroll
            for (int q = 0; q < 16; q++) pr[q] += v * eW1[(1 + k) * 16 + q];
        }
        float4* pw = reinterpret_cast<float4*>(&sPr[tid][0]);
#pragma unroll
        for (int t4 = 0; t4 < 4; t4++)
            pw[t4] = make_float4(pr[4*t4], pr[4*t4+1], pr[4*t4+2], pr[4*t4+3]);
    }
    __syncthreads();

    // ---- registerize ALL edge-loop weights: 208 VGPRs, loaded once ----
    float cw[128], aw[32], ow[32], gterm[16];
    {
        const float4* W4 = reinterpret_cast<const float4*>(eW1 + 9 * 16);
#pragma unroll
        for (int i = 0; i < 32; i++) {
            float4 w = W4[i];
            cw[4*i] = w.x; cw[4*i+1] = w.y; cw[4*i+2] = w.z; cw[4*i+3] = w.w;
        }
        const float4* A4 = reinterpret_cast<const float4*>(eW1 + 17 * 16);
#pragma unroll
        for (int i = 0; i < 8; i++) {
            float4 w = A4[i];
            aw[4*i] = w.x; aw[4*i+1] = w.y; aw[4*i+2] = w.z; aw[4*i+3] = w.w;
        }
        const float4* O4 = reinterpret_cast<const float4*>(eW2);
#pragma unroll
        for (int i = 0; i < 8; i++) {
            float4 w = O4[i];
            ow[4*i] = w.x; ow[4*i+1] = w.y; ow[4*i+2] = w.z; ow[4*i+3] = w.w;
        }
#pragma unroll
        for (int q = 0; q < 16; q++) gterm[q] = eB1[q] + gval * eW1[q];
    }
    float b20 = eB2[0], b21 = eB2[1];

    int e0b = b_off[b], e1b = b_off[b + 1];
    int qlen = (e1b - e0b + SUB - 1) / SUB;
    int es = e0b + s * qlen;
    int ee = min(e1b, es + qlen);

    float t0 = 0.f, t1 = 0.f;
    for (int e = es + tid; e < ee; e += 256) {
        float4 r = rec[e];
        int li  = __float_as_int(r.x) - n0;
        int col = __float_as_int(r.y);
        const float4* xc4 = reinterpret_cast<const float4*>(xin + (size_t)col * 8);
        float4 c0 = xc4[0], c1 = xc4[1];
        const float4* pr4 = reinterpret_cast<const float4*>(&sPr[li][0]);
        float4 p0 = pr4[0], p1 = pr4[1], p2 = pr4[2], p3 = pr4[3];
        float h[16];
        h[0]  = gterm[0]  + p0.x; h[1]  = gterm[1]  + p0.y;
        h[2]  = gterm[2]  + p0.z; h[3]  = gterm[3]  + p0.w;
        h[4]  = gterm[4]  + p1.x; h[5]  = gterm[5]  + p1.y;
        h[6]  = gterm[6]  + p1.z; h[7]  = gterm[7]  + p1.w;
        h[8]  = gterm[8]  + p2.x; h[9]  = gterm[9]  + p2.y;
        h[10] = gterm[10] + p2.z; h[11] = gterm[11] + p2.w;
        h[12] = gterm[12] + p3.x; h[13] = gterm[13] + p3.y;
        h[14] = gterm[14] + p3.z; h[15] = gterm[15] + p3.w;
        float xc[8] = {c0.x, c0.y, c0.z, c0.w, c1.x, c1.y, c1.z, c1.w};
#pragma unroll
        for (int k = 0; k < 8; k++) {
            float v = xc[k];
#pragma unroll
            for (int q = 0; q < 16; q++) h[q] += v * cw[k * 16 + q];
        }
#pragma unroll
        for (int q = 0; q < 16; q++) h[q] += r.z * aw[q] + r.w * aw[16 + q];
        float s0 = b20, s1 = b21;
#pragma unroll
        for (int q = 0; q < 16; q++) {
            float rr = fmaxf(h[q], 0.f);
            s0 += rr * ow[2 * q];
            s1 += rr * ow[2 * q + 1];
        }
        if (WRITE_EMB) rec[e] = make_float4(r.x, r.y, s0, s1);
        atomicAdd(&sagg[li][0], s0);
        atomicAdd(&sagg[li][1], s1);
        t0 += s0; t1 += s1;
    }

    if (NEED_SUM) {
        float r0 = wave_red(t0), r1 = wave_red(t1);
        int wave = tid >> 6, lane = tid & 63;
        if (lane == 0) { redE[wave][0] = r0; redE[wave][1] = r1; }
    }
    __syncthreads();   // sagg complete (and redE visible)
    pagg[((size_t)s * NBUCK + b) * 256 + tid] =
        make_float2(sagg[tid][0], sagg[tid][1]);
    if (NEED_SUM && tid == 0) {
        atomicAdd(&sums[0], redE[0][0] + redE[1][0] + redE[2][0] + redE[3][0]);
        atomicAdd(&sums[1], redE[0][1] + redE[1][1] + redE[2][1] + redE[3][1]);
    }
}

// ============ node kernel: sum SUB partials + node MLP =======================
template <bool NEED_SUM>
__global__ __launch_bounds__(256) void node_kernel(
    const float* __restrict__ xin, const float2* __restrict__ pagg,
    const float* __restrict__ gptr,
    const float* __restrict__ nW1, const float* __restrict__ nB1,
    const float* __restrict__ nW2, const float* __restrict__ nB2,
    float* __restrict__ xout, float* __restrict__ sums)
{
    __shared__ float redN[4][8];
    int tid = threadIdx.x, b = blockIdx.x;
    int n = b * 256 + tid;
    float out[8];
#pragma unroll
    for (int m = 0; m < 8; m++) out[m] = 0.f;

    if (n < NN) {
        float ag0 = 0.f, ag1 = 0.f;
#pragma unroll
        for (int s = 0; s < SUB; s++) {
            float2 p = pagg[((size_t)s * NBUCK + b) * 256 + tid];
            ag0 += p.x; ag1 += p.y;
        }
        float gval = gptr[0];
        float in[11];
        in[0] = gval;
        const float4* xi = reinterpret_cast<const float4*>(xin + (size_t)n * 8);
        float4 a0 = xi[0], a1 = xi[1];
        in[1] = a0.x; in[2] = a0.y; in[3] = a0.z; in[4] = a0.w;
        in[5] = a1.x; in[6] = a1.y; in[7] = a1.z; in[8] = a1.w;
        in[9] = ag0; in[10] = ag1;

        float h[16];
#pragma unroll
        for (int q = 0; q < 16; q++) h[q] = nB1[q];
#pragma unroll
        for (int k = 0; k < 11; k++) {
            float v = in[k];
#pragma unroll
            for (int q = 0; q < 16; q++) h[q] += v * nW1[k * 16 + q];
        }
#pragma unroll
        for (int m = 0; m < 8; m++) out[m] = nB2[m];
#pragma unroll
        for (int q = 0; q < 16; q++) {
            float hq = fmaxf(h[q], 0.f);
#pragma unroll
            for (int m = 0; m < 8; m++) out[m] += hq * nW2[q * 8 + m];
        }
        float4* xo = reinterpret_cast<float4*>(xout + (size_t)n * 8);
        xo[0] = make_float4(out[0], out[1], out[2], out[3]);
        xo[1] = make_float4(out[4], out[5], out[6], out[7]);
    }
    if (NEED_SUM) {
        float r[8];
#pragma unroll
        for (int m = 0; m < 8; m++) r[m] = wave_red(out[m]);
        int wave = tid >> 6, lane = tid & 63;
        if (lane == 0) {
#pragma unroll
            for (int m = 0; m < 8; m++) redN[wave][m] = r[m];
        }
        __syncthreads();
        if (tid == 0) {
#pragma unroll
            for (int m = 0; m < 8; m++) {
                float s = redN[0][m] + redN[1][m] + redN[2][m] + redN[3][m];
                atomicAdd(&sums[2 + m], s);
            }
        }
    }
}

// ---------------- global block: MLP(11->16->1), single thread ----------------
__global__ void glob_kernel(const float* __restrict__ sums,
                            const float* __restrict__ gold,
                            const float* __restrict__ W1, const float* __restrict__ B1,
                            const float* __restrict__ W2, const float* __restrict__ B2,
                            float* __restrict__ gnew)
{
    if (threadIdx.x == 0 && blockIdx.x == 0) {
        float in[11];
#pragma unroll
        for (int j = 0; j < 8; j++) in[j] = sums[2 + j] * (1.0f / NN);
        in[8] = sums[0] * (1.0f / NE);
        in[9] = sums[1] * (1.0f / NE);
        in[10] = gold[0];
        float acc = B2[0];
#pragma unroll
        for (int j = 0; j < 16; j++) {
            float h = B1[j];
#pragma unroll
            for (int k = 0; k < 11; k++) h += in[k] * W1[k * 16 + j];
            acc += fmaxf(h, 0.f) * W2[j];
        }
        gnew[0] = acc;
    }
}

extern "C" void kernel_launch(void* const* d_in, const int* in_sizes, int n_in,
                              void* d_out, int out_size, void* d_ws, size_t ws_size,
                              hipStream_t stream) {
    const float* x     = (const float*)d_in[0];
    const int*   ei    = (const int*)d_in[1];
    const float* eattr = (const float*)d_in[2];
    const float* g     = (const float*)d_in[3];
    const float* eW1 = (const float*)d_in[4];
    const float* eB1 = (const float*)d_in[5];
    const float* eW2 = (const float*)d_in[6];
    const float* eB2 = (const float*)d_in[7];
    const float* nW1 = (const float*)d_in[8];
    const float* nB1 = (const float*)d_in[9];
    const float* nW2 = (const float*)d_in[10];
    const float* nB2 = (const float*)d_in[11];
    const float* gW1 = (const float*)d_in[12];
    const float* gB1 = (const float*)d_in[13];
    const float* gW2 = (const float*)d_in[14];
    const float* gB2 = (const float*)d_in[15];
    float* out = (float*)d_out;

    char* ws = (char*)d_ws;
    float*  xb0   = (float*)(ws);                  // 3,200,000
    float*  xb1   = (float*)(ws + 3200000);        // 3,200,000 -> 6,400,000
    int*    b_off = (int*)  (ws + 6400000);        // 392*4 -> pad 1,600
    float*  sums  = (float*)(ws + 6401600);        // 128 B
    float*  g1    = (float*)(ws + 6401728);
    float*  g2    = g1 + 1;
    float4* rec   = (float4*)(ws + 6401792);       // 25,600,000 -> 32,001,792
    float2* pagg  = (float2*)(ws + 32001792);      // 4*391*256*8 = 3,203,072 -> 35,204,864
    // build-phase temporaries alias xb1 (dead until layer-1 node kernel):
    int*    hist     = (int*)xb1;                          // 391*391*4 = 611,524
    int*    baseT    = (int*)((char*)xb1 + 611584);        // 611,524
    int*    colTotal = (int*)((char*)xb1 + 1223168);       // 1,564

    dim3 blk(256);
    dim3 cgrid(NCHUNK);                            // 391 chunks
    dim3 bgrid(NBUCK);                             // 391 buckets
    dim3 egrid(NBUCK * SUB);                       // 1564 edge sub-blocks

    // ---- bucket-sort build (no global atomics) ----
    hipMemsetAsync(sums, 0, 128, stream);
    hist_kernel<<<cgrid, blk, 0, stream>>>(ei, hist);
    bscan_kernel<<<bgrid, 512, 0, stream>>>(hist, baseT, colTotal);
    boff_kernel<<<1, 512, 0, stream>>>(colTotal, b_off);
    fillb_kernel<<<cgrid, blk, 0, stream>>>(ei, eattr, baseT, b_off, rec);

    // ---- layer 0: x(d_in) -> xb0; rec.zw: ea -> L0 edge emb ----
    edge_kernel<true, true><<<egrid, blk, 0, stream>>>(
        rec, b_off, g, eW1, eB1, eW2, eB2, x, pagg, sums);
    node_kernel<true><<<bgrid, blk, 0, stream>>>(
        x, pagg, g, nW1, nB1, nW2, nB2, xb0, sums);
    glob_kernel<<<1, 64, 0, stream>>>(sums, g, gW1, gB1, gW2, gB2, g1);

    // ---- layer 1: xb0 -> xb1; rec.zw: L0 -> L1 emb ----
    edge_kernel<true, true><<<egrid, blk, 0, stream>>>(
        rec, b_off, g1, eW1 + 304, eB1 + 16, eW2 + 32, eB2 + 2, xb0, pagg, sums + 16);
    node_kernel<true><<<bgrid, blk, 0, stream>>>(
        xb0, pagg, g1, nW1 + 176, nB1 + 16, nW2 + 128, nB2 + 8, xb1, sums + 16);
    glob_kernel<<<1, 64, 0, stream>>>(sums + 16, g1, gW1 + 176, gB1 + 16, gW2 + 16, gB2 + 1, g2);

    // ---- layer 2: xb1 -> d_out; no emb rewrite, no sums ----
    edge_kernel<false, false><<<egrid, blk, 0, stream>>>(
        rec, b_off, g2, eW1 + 608, eB1 + 32, eW2 + 64, eB2 + 4, xb1, pagg, sums);
    node_kernel<false><<<bgrid, blk, 0, stream>>>(
        xb1, pagg, g2, nW1 + 352, nB1 + 32, nW2 + 256, nB2 + 16, out, sums);
}